// Round 8
// baseline (301.793 us; speedup 1.0000x reference)
//
#include <hip/hip_runtime.h>

#define CUR 512
#define FULLS 1024
#define BSZ 8
#define DIMM 1024
#define NH 16
#define HD 64

typedef __attribute__((ext_vector_type(8))) short short8;
typedef __attribute__((ext_vector_type(4))) float floatx4;

__device__ __forceinline__ unsigned short f2bf(float x) {
  unsigned int u = __float_as_uint(x);
  unsigned int r = (u + 0x7fffu + ((u >> 16) & 1u)) >> 16;
  return (unsigned short)r;
}
__device__ __forceinline__ float bf2f(unsigned short h) {
  return __uint_as_float(((unsigned int)h) << 16);
}
// pack two floats to bf16x2 (round-to-nearest-even)
__device__ __forceinline__ unsigned int pack2rn(float a, float b) {
  return (unsigned int)f2bf(a) | ((unsigned int)f2bf(b) << 16);
}
// pack two floats to bf16x2 (truncate — bias cancels in softmax normalization)
__device__ __forceinline__ unsigned int pack2tr(float a, float b) {
  return (__float_as_uint(a) >> 16) | (__float_as_uint(b) & 0xffff0000u);
}

__device__ __forceinline__ void async16(void* lds, const void* g) {
  __builtin_amdgcn_global_load_lds(
      (const __attribute__((address_space(1))) unsigned int*)g,
      (__attribute__((address_space(3))) unsigned int*)lds, 16, 0, 0);
}

// ---------------------------------------------------------------------------
// Fused prep: all fp32->bf16 casts + weight transpose-casts in ONE launch.
// ---------------------------------------------------------------------------
__global__ __launch_bounds__(256)
void prep_kernel(const float* __restrict__ fi, short* __restrict__ fi_bf,
                 const float* __restrict__ inp, short* __restrict__ in_bf,
                 const float* __restrict__ pe, short* __restrict__ pe_bf,
                 const float* __restrict__ Wkv, short* __restrict__ Wkv_t,
                 const float* __restrict__ Wq, short* __restrict__ Wq_t,
                 const float* __restrict__ Wpos, short* __restrict__ Wpos_t,
                 const float* __restrict__ Wproj, short* __restrict__ Wproj_t) {
  __shared__ float t[64][65];
  const int blk = blockIdx.x;
  const int tid = threadIdx.x;
  if (blk < 6656) {
    const float* x; short* y; int base;
    if (blk < 4096)      { x = fi;  y = fi_bf; base = blk; }
    else if (blk < 6144) { x = inp; y = in_bf; base = blk - 4096; }
    else                 { x = pe;  y = pe_bf; base = blk - 6144; }
    int i = (base * 256 + tid) * 8;
    float a[8];
    *(float4*)&a[0] = *(const float4*)&x[i];
    *(float4*)&a[4] = *(const float4*)&x[i + 4];
    short8 o;
    #pragma unroll
    for (int j = 0; j < 8; ++j) o[j] = f2bf(a[j]);
    *(short8*)&y[i] = o;
    return;
  }
  const float* W; short* Wt; int N, t2;
  if (blk < 7168)      { W = Wkv;   Wt = Wkv_t;   N = 2048; t2 = blk - 6656; }
  else if (blk < 7424) { W = Wq;    Wt = Wq_t;    N = 1024; t2 = blk - 7168; }
  else if (blk < 7680) { W = Wpos;  Wt = Wpos_t;  N = 1024; t2 = blk - 7424; }
  else                 { W = Wproj; Wt = Wproj_t; N = 1024; t2 = blk - 7680; }
  const int K = 1024;
  const int nx = N / 64;
  const int n0 = (t2 % nx) * 64, k0 = (t2 / nx) * 64;
  #pragma unroll
  for (int r = 0; r < 4; ++r) {
    int f = tid + r * 256;
    int row = f >> 4, c = (f & 15) * 4;
    float4 v = *(const float4*)&W[(size_t)(k0 + row) * N + n0 + c];
    t[c + 0][row] = v.x; t[c + 1][row] = v.y;
    t[c + 2][row] = v.z; t[c + 3][row] = v.w;
  }
  __syncthreads();
  #pragma unroll
  for (int r = 0; r < 2; ++r) {
    int f = tid + r * 256;
    int row = f >> 3, c = (f & 7) * 8;
    short8 o;
    #pragma unroll
    for (int j = 0; j < 8; ++j) o[j] = f2bf(t[row][c + j]);
    *(short8*)&Wt[(size_t)(n0 + row) * K + k0 + c] = o;
  }
}

// ---------------------------------------------------------------------------
// bf16 MFMA GEMM body: C[M,N] = A[M,K] @ Bt[N,K]^T + bias. 128x128 tile.
// ---------------------------------------------------------------------------
__device__ __forceinline__
void gemm_body(short* As, short* Bs,
               const short* __restrict__ A, const short* __restrict__ Bt,
               const float* __restrict__ bias, void* __restrict__ Cp,
               int M, int N, int K, int out_bf16, int bx, int by) {
  const int tid = threadIdx.x;
  const int w = tid >> 6, lane = tid & 63, l15 = lane & 15, quad = lane >> 4;
  const int m0 = by * 128, n0 = bx * 128;
  const int wm = (w & 1) * 64, wn = (w >> 1) * 64;

  floatx4 acc[4][4];
  #pragma unroll
  for (int i = 0; i < 4; ++i)
    #pragma unroll
    for (int j = 0; j < 4; ++j) acc[i][j] = (floatx4){0.f, 0.f, 0.f, 0.f};

  for (int k0 = 0; k0 < K; k0 += 32) {
    __syncthreads();
    #pragma unroll
    for (int rnd = 0; rnd < 2; ++rnd) {
      int fb = rnd * 256 + w * 64;
      int f = fb + lane;
      int row = f >> 2, c = f & 3;
      int cs = (c ^ (row & 3)) * 8;
      async16(As + fb * 8, &A[(size_t)(m0 + row) * K + k0 + cs]);
      async16(Bs + fb * 8, &Bt[(size_t)(n0 + row) * K + k0 + cs]);
    }
    __syncthreads();
    short8 af[4], bf[4];
    #pragma unroll
    for (int t = 0; t < 4; ++t) {
      int swz = ((quad ^ (l15 & 3)) * 8);
      af[t] = *(const short8*)&As[(wm + t * 16 + l15) * 32 + swz];
      bf[t] = *(const short8*)&Bs[(wn + t * 16 + l15) * 32 + swz];
    }
    #pragma unroll
    for (int mt = 0; mt < 4; ++mt)
      #pragma unroll
      for (int nt = 0; nt < 4; ++nt)
        acc[mt][nt] = __builtin_amdgcn_mfma_f32_16x16x32_bf16(
            af[mt], bf[nt], acc[mt][nt], 0, 0, 0);
  }

  #pragma unroll
  for (int mt = 0; mt < 4; ++mt)
    #pragma unroll
    for (int nt = 0; nt < 4; ++nt)
      #pragma unroll
      for (int r = 0; r < 4; ++r) {
        int row = m0 + wm + mt * 16 + quad * 4 + r;
        int col = n0 + wn + nt * 16 + l15;
        float v = acc[mt][nt][r] + bias[col];
        if (out_bf16) ((short*)Cp)[(size_t)row * N + col] = (short)f2bf(v);
        else          ((float*)Cp)[(size_t)row * N + col] = v;
      }
}

// Fused input projections (static grid: R7's work-stealing regressed).
// Tiles: 0..1023 kv, 1024..1279 q, 1280..1343 r.
__global__ __launch_bounds__(256)
void proj_gemm_kernel(const short* __restrict__ fi_bf, const short* __restrict__ Wkv_t,
                      const float* __restrict__ b_kv, short* __restrict__ kv_bf,
                      const short* __restrict__ in_bf, const short* __restrict__ Wq_t,
                      const float* __restrict__ b_q, float* __restrict__ q_f32,
                      const short* __restrict__ pe_bf, const short* __restrict__ Wpos_t,
                      const float* __restrict__ b_pos, short* __restrict__ r_bf) {
  __shared__ short As[128 * 32];
  __shared__ short Bs[128 * 32];
  const int blk = blockIdx.x;
  if (blk < 1024)
    gemm_body(As, Bs, fi_bf, Wkv_t, b_kv, kv_bf, 8192, 2048, 1024, 1,
              blk % 16, blk / 16);
  else if (blk < 1280) {
    int tb = blk - 1024;
    gemm_body(As, Bs, in_bf, Wq_t, b_q, q_f32, 4096, 1024, 1024, 0,
              tb % 8, tb / 8);
  } else {
    int tb = blk - 1280;
    gemm_body(As, Bs, pe_bf, Wpos_t, b_pos, r_bf, 1024, 1024, 1024, 1,
              tb % 8, tb / 8);
  }
}

// ---------------------------------------------------------------------------
// Output projection: 64x128 tiles, 512 blocks (2/CU, 8 waves/CU).
// ---------------------------------------------------------------------------
__global__ __launch_bounds__(256)
void out_gemm_kernel(const short* __restrict__ av_bf, const short* __restrict__ Wproj_t,
                     const float* __restrict__ b_proj, float* __restrict__ out) {
  __shared__ short As[64 * 32];
  __shared__ short Bs[128 * 32];
  const int tid = threadIdx.x;
  const int w = tid >> 6, lane = tid & 63, l15 = lane & 15, quad = lane >> 4;
  const int m0 = (blockIdx.x >> 3) * 64, n0 = (blockIdx.x & 7) * 128;
  const int wm = (w & 1) * 32, wn = (w >> 1) * 64;
  const int N = 1024, K = 1024;

  floatx4 acc[2][4];
  #pragma unroll
  for (int i = 0; i < 2; ++i)
    #pragma unroll
    for (int j = 0; j < 4; ++j) acc[i][j] = (floatx4){0.f, 0.f, 0.f, 0.f};

  for (int k0 = 0; k0 < K; k0 += 32) {
    __syncthreads();
    {
      int f = w * 64 + lane;
      int row = f >> 2, c = f & 3;
      int cs = (c ^ (row & 3)) * 8;
      async16(As + f * 8, &av_bf[(size_t)(m0 + row) * K + k0 + cs]);
      #pragma unroll
      for (int rnd = 0; rnd < 2; ++rnd) {
        int fb = rnd * 256 + w * 64;
        int f2 = fb + lane;
        int row2 = f2 >> 2, c2 = f2 & 3;
        int cs2 = (c2 ^ (row2 & 3)) * 8;
        async16(Bs + fb * 8, &Wproj_t[(size_t)(n0 + row2) * K + k0 + cs2]);
      }
    }
    __syncthreads();
    short8 af[2], bf[4];
    #pragma unroll
    for (int t = 0; t < 2; ++t) {
      int swz = ((quad ^ (l15 & 3)) * 8);
      af[t] = *(const short8*)&As[(wm + t * 16 + l15) * 32 + swz];
    }
    #pragma unroll
    for (int t = 0; t < 4; ++t) {
      int swz = ((quad ^ (l15 & 3)) * 8);
      bf[t] = *(const short8*)&Bs[(wn + t * 16 + l15) * 32 + swz];
    }
    #pragma unroll
    for (int mt = 0; mt < 2; ++mt)
      #pragma unroll
      for (int nt = 0; nt < 4; ++nt)
        acc[mt][nt] = __builtin_amdgcn_mfma_f32_16x16x32_bf16(
            af[mt], bf[nt], acc[mt][nt], 0, 0, 0);
  }

  #pragma unroll
  for (int mt = 0; mt < 2; ++mt)
    #pragma unroll
    for (int nt = 0; nt < 4; ++nt)
      #pragma unroll
      for (int r = 0; r < 4; ++r) {
        int row = m0 + wm + mt * 16 + quad * 4 + r;
        int col = n0 + wn + nt * 16 + l15;
        out[(size_t)row * N + col] = acc[mt][nt][r] + b_proj[col];
      }
}

// ---------------------------------------------------------------------------
// "Transpose-world" pipelined MFMA flash attention.
// S^T = mfma(K_frag, Q_frag): lane owns query=l15, keys=quad*4+r+16*nt.
//  - P^T / Ptilde^T writes: 4 ds_write_b64 each (was 16 ds_write_u16)
//  - Pb: single buffer, two phase-halves; gather = 1 ds_read_u16/elem
//  - R window staged in REGISTERS (prefetched 1 iter ahead): Rs LDS deleted
//  - O^T = mfma(Vt_frag, P^T_frag); epilogue packs bf16x2, per-lane lsum
// Pb/Pt2 are wave-private: no extra barriers. LDS 58.9 KB -> 2 blocks/CU.
// ---------------------------------------------------------------------------
__global__ __launch_bounds__(256, 2)
void attn_mfma_kernel(const float* __restrict__ qf, const short* __restrict__ kvb,
                      const short* __restrict__ rb, const float* __restrict__ um,
                      const float* __restrict__ vm, short* __restrict__ avb) {
  const int h = blockIdx.x, qt = blockIdx.y, b = blockIdx.z;
  const int tid = threadIdx.x;
  const int w = tid >> 6, lane = tid & 63, l15 = lane & 15, quad = lane >> 4;
  const float SCL2E = 0.125f * 1.44269504089f;

  __shared__ short Ks[2][64 * 64];         // [buf][key][chunk-swizzled d]
  __shared__ unsigned int Vt[2][64 * 32];  // [buf][d][key-pair], swizzled
  __shared__ short Pb[64 * 132];           // [query][2 phase-halves of 64]
  __shared__ short Pt2[4][16 * 72];        // per-wave P[query][key]

  const int jtmax = qt + 8;
  const int iloc = w * 16 + l15;           // block-local query row

  // ---- Q fragments (B-op layout == A-op layout per lane), pre-scaled ----
  short8 qu_[2], qv_[2];
  {
    size_t gbase = ((size_t)(qt * 64 + iloc) * BSZ + b) * 1024 + h * 64;
    #pragma unroll
    for (int ks = 0; ks < 2; ++ks) {
      int d0 = ks * 32 + quad * 8;
      float qa[8], ua[8], va[8];
      *(float4*)&qa[0] = *(const float4*)&qf[gbase + d0];
      *(float4*)&qa[4] = *(const float4*)&qf[gbase + d0 + 4];
      *(float4*)&ua[0] = *(const float4*)&um[h * 64 + d0];
      *(float4*)&ua[4] = *(const float4*)&um[h * 64 + d0 + 4];
      *(float4*)&va[0] = *(const float4*)&vm[h * 64 + d0];
      *(float4*)&va[4] = *(const float4*)&vm[h * 64 + d0 + 4];
      #pragma unroll
      for (int j = 0; j < 8; ++j) {
        qu_[ks][j] = f2bf((qa[j] + ua[j]) * SCL2E);
        qv_[ks][j] = f2bf((qa[j] + va[j]) * SCL2E);
      }
    }
  }

  auto stage_K = [&](int buf, int jt) {
    #pragma unroll
    for (int rnd = 0; rnd < 2; ++rnd) {
      int fb = rnd * 256 + w * 64;
      int f = fb + lane;
      int row = f >> 3, c = f & 7;
      int cs = (c ^ (row & 7)) * 8;
      async16(&Ks[buf][fb * 8],
              &kvb[((size_t)(jt * 64 + row) * BSZ + b) * 2048 + h * 64 + cs]);
    }
  };
  const int dc = tid & 7, kp = tid >> 3;
  short8 vra, vrb;
  auto loadV = [&](int jt) {
    size_t g0 = ((size_t)(jt * 64 + kp * 2) * BSZ + b) * 2048 + 1024 + h * 64 + dc * 8;
    vra = *(const short8*)&kvb[g0];
    vrb = *(const short8*)&kvb[g0 + 2048 * BSZ];
  };
  auto packV = [&](int buf) {
    #pragma unroll
    for (int i = 0; i < 8; ++i) {
      int d = dc * 8 + i;
      int swz = (i ^ dc) & 7;
      Vt[buf][d * 32 + (((kp >> 2) ^ swz) * 4) + (kp & 3)] =
          (unsigned int)(unsigned short)vra[i] |
          ((unsigned int)(unsigned short)vrb[i] << 16);
    }
  };
  // R window -> registers (A-op layout: m = window row, k = d)
  auto rloadW = [&](int p0, short8 (&R)[4][2]) {
    #pragma unroll
    for (int nt = 0; nt < 4; ++nt)
      #pragma unroll
      for (int ks = 0; ks < 2; ++ks)
        R[nt][ks] = *(const short8*)
            &rb[(size_t)(p0 + nt * 16 + l15) * 1024 + h * 64 + ks * 32 + quad * 8];
  };
  // Ptilde^T chunk: rows = window cols (nt*16+quad*4+r), cols = query l15.
  auto compute_chunkT = [&](int ph, short8 (&R)[4][2]) {
    #pragma unroll
    for (int nt = 0; nt < 4; ++nt) {
      floatx4 a = (floatx4){0.f, 0.f, 0.f, 0.f};
      a = __builtin_amdgcn_mfma_f32_16x16x32_bf16(R[nt][0], qv_[0], a, 0, 0, 0);
      a = __builtin_amdgcn_mfma_f32_16x16x32_bf16(R[nt][1], qv_[1], a, 0, 0, 0);
      uint2 pk;
      pk.x = pack2rn(a[0], a[1]);
      pk.y = pack2rn(a[2], a[3]);
      *(uint2*)&Pb[iloc * 132 + 64 * ph + nt * 16 + quad * 4] = pk;
    }
  };

  short8 RA[4][2], RB[4][2];

  // ---- prologue ----
  rloadW(448 - qt * 64, RA);         // prologue chunk window
  stage_K(0, 0);
  loadV(0);
  packV(0);
  compute_chunkT(1, RA);             // prologue chunk -> phase-half 1
  rloadW(512 - qt * 64, RA);         // window for jt=0
  __syncthreads();

  float lsum = 0.f;
  floatx4 O[4];
  #pragma unroll
  for (int nt = 0; nt < 4; ++nt) O[nt] = (floatx4){0.f, 0.f, 0.f, 0.f};

  auto iter = [&](int jt, short8 (&Rc)[4][2], short8 (&Rn)[4][2]) {
    const int cur = jt & 1, nxt = cur ^ 1;

    if (jt < jtmax) { stage_K(nxt, jt + 1); loadV(jt + 1); }
    if (jt + 1 < jtmax) rloadW(512 + 64 * (jt + 1 - qt), Rn);
    if (jt < jtmax) compute_chunkT(cur, Rc);

    // ---- content scores S^T (rows=keys, cols=queries) ----
    floatx4 S[4];
    #pragma unroll
    for (int nt = 0; nt < 4; ++nt) {
      S[nt] = (floatx4){0.f, 0.f, 0.f, 0.f};
      #pragma unroll
      for (int ks = 0; ks < 2; ++ks) {
        short8 kf = *(const short8*)
            &Ks[cur][(nt * 16 + l15) * 64 + (((ks * 4 + quad) ^ (l15 & 7)) * 8)];
        S[nt] = __builtin_amdgcn_mfma_f32_16x16x32_bf16(kf, qu_[ks], S[nt], 0, 0, 0);
      }
    }

    // ---- rel-shift gather (single-phase Pb) + mask + exp2 ----
    const int coff = 64 * (1 - (jt & 1));
    const int pbase = iloc * 132;
    #pragma unroll
    for (int nt = 0; nt < 4; ++nt) {
      #pragma unroll
      for (int r = 0; r < 4; ++r) {
        int jl = nt * 16 + quad * 4 + r;
        int rel = jl - iloc + 63;
        int col = (rel + coff) & 127;
        float pos = bf2f((unsigned short)Pb[pbase + col]);
        float z = S[nt][r] + pos;
        if (jt == jtmax && jl > iloc) z = -1e30f;
        float e = __builtin_amdgcn_exp2f(z);
        S[nt][r] = e;
        lsum += e;
      }
    }

    // ---- P^T -> LDS (4 x ds_write_b64, truncating pack), read B-frag ----
    #pragma unroll
    for (int nt = 0; nt < 4; ++nt) {
      uint2 pk;
      pk.x = pack2tr(S[nt][0], S[nt][1]);
      pk.y = pack2tr(S[nt][2], S[nt][3]);
      *(uint2*)&Pt2[w][l15 * 72 + nt * 16 + quad * 4] = pk;
    }
    short8 pf[2];
    #pragma unroll
    for (int ks = 0; ks < 2; ++ks)
      pf[ks] = *(const short8*)&Pt2[w][l15 * 72 + ks * 32 + quad * 8];

    // ---- O^T += V^T @ P^T ----
    #pragma unroll
    for (int ntd = 0; ntd < 4; ++ntd) {
      int d = ntd * 16 + l15;
      int swv = (d ^ (d >> 3)) & 7;
      short8 vfr = *(const short8*)&Vt[cur][d * 32 + ((quad ^ swv) * 4)];
      short8 vfr2 = *(const short8*)&Vt[cur][d * 32 + (((4 + quad) ^ swv) * 4)];
      O[ntd] = __builtin_amdgcn_mfma_f32_16x16x32_bf16(vfr, pf[0], O[ntd], 0, 0, 0);
      O[ntd] = __builtin_amdgcn_mfma_f32_16x16x32_bf16(vfr2, pf[1], O[ntd], 0, 0, 0);
    }

    if (jt < jtmax) packV(nxt);
    __syncthreads();
  };

  for (int jt = 0; jt <= jtmax; jt += 2) {
    iter(jt, RA, RB);
    if (jt + 1 <= jtmax) iter(jt + 1, RB, RA);
  }

  // ---- epilogue: per-lane lsum, cross-quad reduce, packed bf16 write ----
  {
    float rs = lsum;
    rs += __shfl_xor(rs, 16);
    rs += __shfl_xor(rs, 32);
    float inv = 1.f / rs;
    size_t gb = ((size_t)(qt * 64 + iloc) * BSZ + b) * 1024 + h * 64;
    #pragma unroll
    for (int ntd = 0; ntd < 4; ++ntd) {
      uint2 pk;
      pk.x = pack2rn(O[ntd][0] * inv, O[ntd][1] * inv);
      pk.y = pack2rn(O[ntd][2] * inv, O[ntd][3] * inv);
      *(uint2*)&avb[gb + ntd * 16 + quad * 4] = pk;
    }
  }
}

// ---------------------------------------------------------------------------
extern "C" void kernel_launch(void* const* d_in, const int* in_sizes, int n_in,
                              void* d_out, int out_size, void* d_ws, size_t ws_size,
                              hipStream_t stream) {
  const float* inputs  = (const float*)d_in[0];
  const float* pos_emb = (const float*)d_in[1];
  const float* full_in = (const float*)d_in[2];
  const float* u       = (const float*)d_in[3];
  const float* v       = (const float*)d_in[4];
  const float* W_kv    = (const float*)d_in[6];
  const float* b_kv    = (const float*)d_in[7];
  const float* W_q     = (const float*)d_in[8];
  const float* b_q     = (const float*)d_in[9];
  const float* W_pos   = (const float*)d_in[10];
  const float* b_pos   = (const float*)d_in[11];
  const float* W_proj  = (const float*)d_in[12];
  const float* b_proj  = (const float*)d_in[13];
  float* out = (float*)d_out;

  char* ws = (char*)d_ws;
  short* fi_bf   = (short*)(ws + 0);          // 8192x1024 bf16  16 MB
  short* in_bf   = (short*)(ws + 16777216);   // 4096x1024 bf16   8 MB
  short* pe_bf   = (short*)(ws + 25165824);   // 1024x1024 bf16   2 MB
  short* Wkv_t   = (short*)(ws + 27262976);   // 2048x1024 bf16   4 MB
  short* Wq_t    = (short*)(ws + 31457280);   // 1024x1024 bf16   2 MB
  short* Wpos_t  = (short*)(ws + 33554432);   // 1024x1024 bf16   2 MB
  short* Wproj_t = (short*)(ws + 35651584);   // 1024x1024 bf16   2 MB
  short* kv_bf   = (short*)(ws + 37748736);   // 8192x2048 bf16  32 MB
  float* q_f32   = (float*)(ws + 71303168);   // 4096x1024 fp32  16 MB
  short* r_bf    = (short*)(ws + 88080384);   // 1024x1024 bf16   2 MB
  short* av_bf   = (short*)(ws + 90177536);   // 4096x1024 bf16   8 MB

  prep_kernel<<<7936, 256, 0, stream>>>(full_in, fi_bf, inputs, in_bf,
                                        pos_emb, pe_bf, W_kv, Wkv_t, W_q, Wq_t,
                                        W_pos, Wpos_t, W_proj, Wproj_t);

  proj_gemm_kernel<<<1344, 256, 0, stream>>>(fi_bf, Wkv_t, b_kv, kv_bf,
                                             in_bf, Wq_t, b_q, q_f32,
                                             pe_bf, Wpos_t, b_pos, r_bf);

  attn_mfma_kernel<<<dim3(NH, 8, BSZ), 256, 0, stream>>>(q_f32, kv_bf, r_bf,
                                                         u, v, av_bf);

  out_gemm_kernel<<<512, 256, 0, stream>>>(av_bf, Wproj_t, b_proj, out);
}